// Round 3
// baseline (177.543 us; speedup 1.0000x reference)
//
#include <hip/hip_runtime.h>
#include <math.h>

#define BDIM 512
#define DDIM 512

constexpr float EPS   = 1e-6f;
constexpr float HEPS  = 0.5e-6f;
constexpr float LN2   = 0.6931471805599453f;
constexpr float LOG2E = 1.4426950408889634f;

__device__ __forceinline__ float wave_reduce_sum(float v) {
  #pragma unroll
  for (int o = 32; o > 0; o >>= 1) v += __shfl_down(v, o, 64);
  return v;
}
__device__ __forceinline__ float wave_reduce_max(float v) {
  #pragma unroll
  for (int o = 32; o > 0; o >>= 1) v = fmaxf(v, __shfl_down(v, o, 64));
  return v;
}

// ---------------------------------------------------------------------------
// Kernel 1: per-row l2-normalize mu; emit interleaved pairs
// pX[r][d] = (n, 0.5*sigma + 0.5*EPS)  so that bd's sv = A.y + B.y.
// Also ld[r] = sum_d ln(sigma+EPS), mrow[r] = mean sigma.
// ---------------------------------------------------------------------------
__global__ __launch_bounds__(256) void prep_kernel(
    const float* __restrict__ mu1, const float* __restrict__ s1,
    const float* __restrict__ mu2, const float* __restrict__ s2,
    float2* __restrict__ pA, float2* __restrict__ pB,
    float* __restrict__ ld,         // ld1 at 0, ld2 at +B
    float* __restrict__ mrow) {     // m1 at 0, m2 at +B
  const int r = blockIdx.x;
  const int which = blockIdx.y;
  const float* __restrict__ mu = which ? mu2 : mu1;
  const float* __restrict__ sg = which ? s2 : s1;
  float2* __restrict__ pout = which ? pB : pA;
  const int t = threadIdx.x;

  const float a  = mu[r * DDIM + t];
  const float b  = mu[r * DDIM + t + 256];
  const float sa = sg[r * DDIM + t];
  const float sb = sg[r * DDIM + t + 256];

  float v0 = a * a + b * b;
  float v1 = __log2f(sa + EPS) + __log2f(sb + EPS);
  float v2 = sa + sb;

  __shared__ float red[3][4];
  __shared__ float sinv;
  const int wid = t >> 6, lane = t & 63;
  v0 = wave_reduce_sum(v0);
  v1 = wave_reduce_sum(v1);
  v2 = wave_reduce_sum(v2);
  if (lane == 0) { red[0][wid] = v0; red[1][wid] = v1; red[2][wid] = v2; }
  __syncthreads();
  if (t == 0) {
    float sq = red[0][0] + red[0][1] + red[0][2] + red[0][3];
    float lg = red[1][0] + red[1][1] + red[1][2] + red[1][3];
    float sm = red[2][0] + red[2][1] + red[2][2] + red[2][3];
    ld[which * BDIM + r]   = LN2 * lg;
    mrow[which * BDIM + r] = sm * (1.0f / DDIM);
    sinv = 1.0f / fmaxf(sqrtf(sq), 1e-12f);
  }
  __syncthreads();
  const float inv = sinv;
  pout[r * DDIM + t]       = make_float2(a * inv, fmaf(0.5f, sa, HEPS));
  pout[r * DDIM + t + 256] = make_float2(b * inv, fmaf(0.5f, sb, HEPS));
}

// ---------------------------------------------------------------------------
// Kernel 2: B^2*D partial pass, NO main-loop barriers.
// Grid (16,16,4), block 256 = 4 waves. Each wave: 32x32 tile (8x8 lanes,
// 4x4 per lane) over a 32-d slice (slice = z*4+wave). Operands read straight
// from global (L2/L1-resident). End: in-block LDS combine of the 4 waves,
// block writes one float4-packed partial per (i,j) at z.
// ---------------------------------------------------------------------------
__global__ __launch_bounds__(256, 4) void bd_kernel(
    const float2* __restrict__ pA, const float2* __restrict__ pB,
    float* __restrict__ t1p, float* __restrict__ ldap,
    float* __restrict__ dacp) {
  const int t  = threadIdx.x;
  const int w  = t >> 6;          // wave 0..3
  const int ln = t & 63;
  const int r  = ln >> 3;         // 0..7
  const int c  = ln & 7;          // 0..7
  const int i0 = blockIdx.y * 32, j0 = blockIdx.x * 32;
  const int z  = blockIdx.z;      // 0..3
  const int d0 = (z * 4 + w) * 32;

  const float4* __restrict__ Ab[4];
  const float4* __restrict__ Bb[4];
  #pragma unroll
  for (int q = 0; q < 4; ++q) {
    Ab[q] = (const float4*)(pA + (i0 + r * 4 + q) * DDIM + d0);
    Bb[q] = (const float4*)(pB + (j0 + c * 4 + q) * DDIM + d0);
  }

  float t1[4][4]  = {};
  float lda[4][4] = {};
  float dac[4][4] = {};

  for (int g = 0; g < 8; ++g) {   // 8 groups of 4 d's (2 float4 steps)
    float m[4][4] = {{1.f,1.f,1.f,1.f},{1.f,1.f,1.f,1.f},
                     {1.f,1.f,1.f,1.f},{1.f,1.f,1.f,1.f}};
    #pragma unroll
    for (int h = 0; h < 2; ++h) { // each float4 = 2 (n,s) pairs
      float4 Ar[4], Br[4];
      #pragma unroll
      for (int q = 0; q < 4; ++q) Ar[q] = Ab[q][g * 2 + h];
      #pragma unroll
      for (int q = 0; q < 4; ++q) Br[q] = Bb[q][g * 2 + h];
      #pragma unroll
      for (int dd = 0; dd < 2; ++dd) {
        float an[4], as[4], bn[4], bs[4];
        #pragma unroll
        for (int q = 0; q < 4; ++q) {
          an[q] = dd ? Ar[q].z : Ar[q].x;
          as[q] = dd ? Ar[q].w : Ar[q].y;
          bn[q] = dd ? Br[q].z : Br[q].x;
          bs[q] = dd ? Br[q].w : Br[q].y;
        }
        #pragma unroll
        for (int ii = 0; ii < 4; ++ii) {
          #pragma unroll
          for (int jj = 0; jj < 4; ++jj) {
            const float sv = as[ii] + bs[jj];
            const float df = an[ii] - bn[jj];
            t1[ii][jj]  = fmaf(df * df, __builtin_amdgcn_rcpf(sv), t1[ii][jj]);
            m[ii][jj]  *= sv;
            dac[ii][jj] = fmaf(an[ii], bn[jj], dac[ii][jj]);
          }
        }
      }
    }
    #pragma unroll
    for (int ii = 0; ii < 4; ++ii)
      #pragma unroll
      for (int jj = 0; jj < 4; ++jj)
        lda[ii][jj] += __log2f(m[ii][jj]);
  }

  // in-block combine: waves 1..3 dump 48 floats/lane; wave 0 reduces+stores.
  __shared__ float cmb[3][64][49];   // stride 49: conflict-free column reads
  if (w > 0) {
    float* p = cmb[w - 1][ln];
    #pragma unroll
    for (int ii = 0; ii < 4; ++ii)
      #pragma unroll
      for (int jj = 0; jj < 4; ++jj) {
        p[ii * 4 + jj]      = t1[ii][jj];
        p[16 + ii * 4 + jj] = lda[ii][jj];
        p[32 + ii * 4 + jj] = dac[ii][jj];
      }
  }
  __syncthreads();
  if (w == 0) {
    #pragma unroll
    for (int g = 0; g < 3; ++g) {
      const float* p = cmb[g][ln];
      #pragma unroll
      for (int ii = 0; ii < 4; ++ii)
        #pragma unroll
        for (int jj = 0; jj < 4; ++jj) {
          t1[ii][jj]  += p[ii * 4 + jj];
          lda[ii][jj] += p[16 + ii * 4 + jj];
          dac[ii][jj] += p[32 + ii * 4 + jj];
        }
    }
    const size_t zb = (size_t)z * BDIM * BDIM;
    #pragma unroll
    for (int ii = 0; ii < 4; ++ii) {
      const size_t o = zb + (size_t)(i0 + r * 4 + ii) * BDIM + j0 + c * 4;
      *(float4*)&t1p[o]  = make_float4(t1[ii][0],  t1[ii][1],  t1[ii][2],  t1[ii][3]);
      *(float4*)&ldap[o] = make_float4(lda[ii][0], lda[ii][1], lda[ii][2], lda[ii][3]);
      *(float4*)&dacp[o] = make_float4(dac[ii][0], dac[ii][1], dac[ii][2], dac[ii][3]);
    }
  }
}

// ---------------------------------------------------------------------------
// Kernel 3: combine z-partials -> sim, pdiag, per-row off-diag max (no atomics)
// One block per row i; thread handles j = t and t+256.
// ---------------------------------------------------------------------------
__global__ __launch_bounds__(256) void combine_kernel(
    const float* __restrict__ t1p, const float* __restrict__ ldap,
    const float* __restrict__ dacp, const float* __restrict__ ld,
    float* __restrict__ sim, float* __restrict__ pmaxf,
    float* __restrict__ pdiag) {
  const int i = blockIdx.x;
  const int t = threadIdx.x;
  const float l1 = ld[i];
  float rmax = 0.f;
  #pragma unroll
  for (int q = 0; q < 2; ++q) {
    const int j = t + q * 256;
    const size_t o = (size_t)i * BDIM + j;
    float t1 = 0.f, lda = 0.f, dac = 0.f;
    #pragma unroll
    for (int zz = 0; zz < 4; ++zz) {
      const size_t idx = (size_t)zz * BDIM * BDIM + o;
      t1 += t1p[idx]; lda += ldap[idx]; dac += dacp[idx];
    }
    const float bd = fmaf(0.125f, t1,
                          0.5f * (LN2 * lda - 0.5f * (l1 + ld[BDIM + j])));
    sim[o] = exp2f(bd * (-LOG2E / (float)DDIM));
    const float p = exp2f((2.0f * LOG2E) * dac);
    if (j == i) pdiag[i] = p;
    else        rmax = fmaxf(rmax, p);
  }
  __shared__ float red[4];
  const int wid = t >> 6, lane = t & 63;
  const float wm = wave_reduce_max(rmax);
  if (lane == 0) red[wid] = wm;
  __syncthreads();
  if (t == 0) pmaxf[i] = fmaxf(fmaxf(red[0], red[1]), fmaxf(red[2], red[3]));
}

// ---------------------------------------------------------------------------
// Kernel 4: per-row and per-column LSE of logits = scale*sim, plus diag.
// ---------------------------------------------------------------------------
__global__ __launch_bounds__(256) void lse_kernel(
    const float* __restrict__ sim, const float* __restrict__ lscale,
    float* __restrict__ lse_row, float* __restrict__ lse_col,
    float* __restrict__ dlog) {
  const int b = blockIdx.x;
  const int t = threadIdx.x;
  const float sc = *lscale;
  const float r0 = sc * sim[b * BDIM + t];
  const float r1 = sc * sim[b * BDIM + t + 256];
  const float c0 = sc * sim[t * BDIM + b];
  const float c1 = sc * sim[(t + 256) * BDIM + b];

  __shared__ float red[4];
  const int wid = t >> 6, lane = t & 63;

  float rm = wave_reduce_max(fmaxf(r0, r1));
  if (lane == 0) red[wid] = rm;
  __syncthreads();
  rm = fmaxf(fmaxf(red[0], red[1]), fmaxf(red[2], red[3]));
  __syncthreads();

  float cm = wave_reduce_max(fmaxf(c0, c1));
  if (lane == 0) red[wid] = cm;
  __syncthreads();
  cm = fmaxf(fmaxf(red[0], red[1]), fmaxf(red[2], red[3]));
  __syncthreads();

  float rs = wave_reduce_sum(exp2f((r0 - rm) * LOG2E) + exp2f((r1 - rm) * LOG2E));
  if (lane == 0) red[wid] = rs;
  __syncthreads();
  rs = red[0] + red[1] + red[2] + red[3];
  __syncthreads();

  float cs = wave_reduce_sum(exp2f((c0 - cm) * LOG2E) + exp2f((c1 - cm) * LOG2E));
  if (lane == 0) red[wid] = cs;
  __syncthreads();
  cs = red[0] + red[1] + red[2] + red[3];

  if (t == 0) {
    lse_row[b] = rm + LN2 * __log2f(rs);
    lse_col[b] = cm + LN2 * __log2f(cs);
    dlog[b]    = sc * sim[b * BDIM + b];
  }
}

// ---------------------------------------------------------------------------
// Kernel 5: final reductions -> 3 scalars.
// ---------------------------------------------------------------------------
__global__ __launch_bounds__(512) void final_kernel(
    const float* __restrict__ pdiag, const float* __restrict__ pmaxf,
    const float* __restrict__ mrow, const float* __restrict__ lse_row,
    const float* __restrict__ lse_col, const float* __restrict__ dlog,
    float* __restrict__ out) {
  const int t = threadIdx.x;  // 0..511
  const float pm = pmaxf[t];
  const float u  = exp2f(-(pdiag[t] / pm) * LOG2E);   // exp(-diag/negmax)
  const float as = 0.5f * (mrow[t] + mrow[BDIM + t]);

  float vals[6];
  vals[0] = u;
  vals[1] = u * u;
  vals[2] = as * as;
  vals[3] = u * as;
  vals[4] = lse_row[t] - dlog[t];
  vals[5] = lse_col[t] - dlog[t];

  __shared__ float red[6][8];
  const int wid = t >> 6, lane = t & 63;
  #pragma unroll
  for (int k = 0; k < 6; ++k) {
    const float v = wave_reduce_sum(vals[k]);
    if (lane == 0) red[k][wid] = v;
  }
  __syncthreads();
  if (t == 0) {
    float s[6];
    #pragma unroll
    for (int k = 0; k < 6; ++k) {
      float a = 0.f;
      #pragma unroll
      for (int w = 0; w < 8; ++w) a += red[k][w];
      s[k] = a;
    }
    const float mean_u = s[0] * (1.0f / BDIM);
    const float cosv = s[3] / fmaxf(sqrtf(s[1]) * sqrtf(s[2]), 1e-24f);
    out[0] = 0.5f * (s[4] + s[5]) * (1.0f / BDIM);  // loss_pro
    out[1] = 2.4f * (1.0f - cosv);                  // loss_rank * 2.4
    out[2] = 0.5f * mean_u;                         // var_loss
  }
}

extern "C" void kernel_launch(void* const* d_in, const int* in_sizes, int n_in,
                              void* d_out, int out_size, void* d_ws, size_t ws_size,
                              hipStream_t stream) {
  const float* mu1 = (const float*)d_in[0];
  const float* s1  = (const float*)d_in[1];
  const float* mu2 = (const float*)d_in[2];
  const float* s2  = (const float*)d_in[3];
  const float* lsc = (const float*)d_in[4];
  float* out = (float*)d_out;

  float* ws      = (float*)d_ws;
  float2* pA     = (float2*)ws;                       // 512*512 float2 (2MB)
  float2* pB     = pA + BDIM * DDIM;                  // 2MB
  float* sim     = (float*)(pB + BDIM * DDIM);        // 1MB
  float* t1p     = sim + BDIM * BDIM;                 // 4 * 1MB
  float* ldap    = t1p + 4 * BDIM * BDIM;             // 4 * 1MB
  float* dacp    = ldap + 4 * BDIM * BDIM;            // 4 * 1MB
  float* ld      = dacp + 4 * BDIM * BDIM;            // 2*512
  float* mrow    = ld + 2 * BDIM;                     // 2*512
  float* pmaxf   = mrow + 2 * BDIM;                   // 512
  float* pdiag   = pmaxf + BDIM;                      // 512
  float* lse_row = pdiag + BDIM;                      // 512
  float* lse_col = lse_row + BDIM;                    // 512
  float* dlog    = lse_col + BDIM;                    // 512

  prep_kernel<<<dim3(BDIM, 2), 256, 0, stream>>>(mu1, s1, mu2, s2, pA, pB,
                                                 ld, mrow);
  bd_kernel<<<dim3(16, 16, 4), 256, 0, stream>>>(pA, pB, t1p, ldap, dacp);
  combine_kernel<<<BDIM, 256, 0, stream>>>(t1p, ldap, dacp, ld, sim, pmaxf,
                                           pdiag);
  lse_kernel<<<BDIM, 256, 0, stream>>>(sim, lsc, lse_row, lse_col, dlog);
  final_kernel<<<1, 512, 0, stream>>>(pdiag, pmaxf, mrow, lse_row, lse_col,
                                      dlog, out);
}

// Round 4
// 115.142 us; speedup vs baseline: 1.5420x; 1.5420x over previous
//
#include <hip/hip_runtime.h>
#include <math.h>

#define BDIM 512
#define DDIM 512

constexpr float EPS   = 1e-6f;
constexpr float HEPS  = 0.5e-6f;
constexpr float LN2   = 0.6931471805599453f;
constexpr float LOG2E = 1.4426950408889634f;

__device__ __forceinline__ float wave_reduce_sum(float v) {
  #pragma unroll
  for (int o = 32; o > 0; o >>= 1) v += __shfl_down(v, o, 64);
  return v;
}
__device__ __forceinline__ float wave_reduce_max(float v) {
  #pragma unroll
  for (int o = 32; o > 0; o >>= 1) v = fmaxf(v, __shfl_down(v, o, 64));
  return v;
}

// ---------------------------------------------------------------------------
// Kernel 1: per-row l2-normalize mu; emit interleaved pairs
// pX[r][d] = (n, 0.5*sigma + 0.5*EPS)  so that bd's sv = A.y + B.y.
// Also ld[r] = sum_d ln(sigma+EPS), mrow[r] = mean sigma.
// ---------------------------------------------------------------------------
__global__ __launch_bounds__(256) void prep_kernel(
    const float* __restrict__ mu1, const float* __restrict__ s1,
    const float* __restrict__ mu2, const float* __restrict__ s2,
    float2* __restrict__ pA, float2* __restrict__ pB,
    float* __restrict__ ld,         // ld1 at 0, ld2 at +B
    float* __restrict__ mrow) {     // m1 at 0, m2 at +B
  const int r = blockIdx.x;
  const int which = blockIdx.y;
  const float* __restrict__ mu = which ? mu2 : mu1;
  const float* __restrict__ sg = which ? s2 : s1;
  float2* __restrict__ pout = which ? pB : pA;
  const int t = threadIdx.x;

  const float a  = mu[r * DDIM + t];
  const float b  = mu[r * DDIM + t + 256];
  const float sa = sg[r * DDIM + t];
  const float sb = sg[r * DDIM + t + 256];

  float v0 = a * a + b * b;
  float v1 = __log2f(sa + EPS) + __log2f(sb + EPS);
  float v2 = sa + sb;

  __shared__ float red[3][4];
  __shared__ float sinv;
  const int wid = t >> 6, lane = t & 63;
  v0 = wave_reduce_sum(v0);
  v1 = wave_reduce_sum(v1);
  v2 = wave_reduce_sum(v2);
  if (lane == 0) { red[0][wid] = v0; red[1][wid] = v1; red[2][wid] = v2; }
  __syncthreads();
  if (t == 0) {
    float sq = red[0][0] + red[0][1] + red[0][2] + red[0][3];
    float lg = red[1][0] + red[1][1] + red[1][2] + red[1][3];
    float sm = red[2][0] + red[2][1] + red[2][2] + red[2][3];
    ld[which * BDIM + r]   = LN2 * lg;
    mrow[which * BDIM + r] = sm * (1.0f / DDIM);
    sinv = 1.0f / fmaxf(sqrtf(sq), 1e-12f);
  }
  __syncthreads();
  const float inv = sinv;
  pout[r * DDIM + t]       = make_float2(a * inv, fmaf(0.5f, sa, HEPS));
  pout[r * DDIM + t + 256] = make_float2(b * inv, fmaf(0.5f, sb, HEPS));
}

// ---------------------------------------------------------------------------
// Kernel 2: B^2*D partial pass, NO main-loop barriers.
// Grid (16,16,4), block 256 = 4 waves, __launch_bounds__(256,3) -> VGPR cap
// 170 (need ~130, no spill). Each wave: 32x32 tile (8x8 lanes, 4x4 per lane)
// over a 32-d slice. Operands straight from global (L1/L2-resident).
// One float4 per row per h-step keeps operand pressure at 32 VGPRs.
// End: LDS combine of 4 waves, wave 0 writes float4 partials at z.
// ---------------------------------------------------------------------------
__global__ __launch_bounds__(256, 3) void bd_kernel(
    const float2* __restrict__ pA, const float2* __restrict__ pB,
    float* __restrict__ t1p, float* __restrict__ ldap,
    float* __restrict__ dacp) {
  const int t  = threadIdx.x;
  const int w  = t >> 6;          // wave 0..3
  const int ln = t & 63;
  const int r  = ln >> 3;         // 0..7
  const int c  = ln & 7;          // 0..7
  const int i0 = blockIdx.y * 32, j0 = blockIdx.x * 32;
  const int z  = blockIdx.z;      // 0..3
  const int d0 = (z * 4 + w) * 32;

  // base of this lane's first A row / B row; row q is +q*256 float4s.
  const float4* __restrict__ Abase = (const float4*)(pA + (i0 + r * 4) * DDIM + d0);
  const float4* __restrict__ Bbase = (const float4*)(pB + (j0 + c * 4) * DDIM + d0);

  float t1[4][4]  = {};
  float lda[4][4] = {};
  float dac[4][4] = {};

  for (int g = 0; g < 8; ++g) {   // 8 groups of 4 d's
    float m[4][4] = {{1.f,1.f,1.f,1.f},{1.f,1.f,1.f,1.f},
                     {1.f,1.f,1.f,1.f},{1.f,1.f,1.f,1.f}};
    #pragma unroll
    for (int h = 0; h < 2; ++h) { // each float4 = 2 (n,s) pairs
      float4 Ar[4], Br[4];
      #pragma unroll
      for (int q = 0; q < 4; ++q) Ar[q] = Abase[q * 256 + g * 2 + h];
      #pragma unroll
      for (int q = 0; q < 4; ++q) Br[q] = Bbase[q * 256 + g * 2 + h];
      #pragma unroll
      for (int dd = 0; dd < 2; ++dd) {
        float an[4], as[4], bn[4], bs[4];
        #pragma unroll
        for (int q = 0; q < 4; ++q) {
          an[q] = dd ? Ar[q].z : Ar[q].x;
          as[q] = dd ? Ar[q].w : Ar[q].y;
          bn[q] = dd ? Br[q].z : Br[q].x;
          bs[q] = dd ? Br[q].w : Br[q].y;
        }
        #pragma unroll
        for (int ii = 0; ii < 4; ++ii) {
          #pragma unroll
          for (int jj = 0; jj < 4; ++jj) {
            const float sv = as[ii] + bs[jj];
            const float df = an[ii] - bn[jj];
            t1[ii][jj]  = fmaf(df * df, __builtin_amdgcn_rcpf(sv), t1[ii][jj]);
            m[ii][jj]  *= sv;
            dac[ii][jj] = fmaf(an[ii], bn[jj], dac[ii][jj]);
          }
        }
      }
    }
    #pragma unroll
    for (int ii = 0; ii < 4; ++ii)
      #pragma unroll
      for (int jj = 0; jj < 4; ++jj)
        lda[ii][jj] += __log2f(m[ii][jj]);
  }

  // in-block combine: waves 1..3 dump 48 floats/lane; wave 0 reduces+stores.
  __shared__ float cmb[3][64][49];   // stride 49: conflict-free column reads
  if (w > 0) {
    float* p = cmb[w - 1][ln];
    #pragma unroll
    for (int ii = 0; ii < 4; ++ii)
      #pragma unroll
      for (int jj = 0; jj < 4; ++jj) {
        p[ii * 4 + jj]      = t1[ii][jj];
        p[16 + ii * 4 + jj] = lda[ii][jj];
        p[32 + ii * 4 + jj] = dac[ii][jj];
      }
  }
  __syncthreads();
  if (w == 0) {
    #pragma unroll
    for (int g = 0; g < 3; ++g) {
      const float* p = cmb[g][ln];
      #pragma unroll
      for (int ii = 0; ii < 4; ++ii)
        #pragma unroll
        for (int jj = 0; jj < 4; ++jj) {
          t1[ii][jj]  += p[ii * 4 + jj];
          lda[ii][jj] += p[16 + ii * 4 + jj];
          dac[ii][jj] += p[32 + ii * 4 + jj];
        }
    }
    const size_t zb = (size_t)z * BDIM * BDIM;
    #pragma unroll
    for (int ii = 0; ii < 4; ++ii) {
      const size_t o = zb + (size_t)(i0 + r * 4 + ii) * BDIM + j0 + c * 4;
      *(float4*)&t1p[o]  = make_float4(t1[ii][0],  t1[ii][1],  t1[ii][2],  t1[ii][3]);
      *(float4*)&ldap[o] = make_float4(lda[ii][0], lda[ii][1], lda[ii][2], lda[ii][3]);
      *(float4*)&dacp[o] = make_float4(dac[ii][0], dac[ii][1], dac[ii][2], dac[ii][3]);
    }
  }
}

// ---------------------------------------------------------------------------
// Kernel 3: combine z-partials -> sim, pdiag, per-row off-diag max (no atomics)
// ---------------------------------------------------------------------------
__global__ __launch_bounds__(256) void combine_kernel(
    const float* __restrict__ t1p, const float* __restrict__ ldap,
    const float* __restrict__ dacp, const float* __restrict__ ld,
    float* __restrict__ sim, float* __restrict__ pmaxf,
    float* __restrict__ pdiag) {
  const int i = blockIdx.x;
  const int t = threadIdx.x;
  const float l1 = ld[i];
  float rmax = 0.f;
  #pragma unroll
  for (int q = 0; q < 2; ++q) {
    const int j = t + q * 256;
    const size_t o = (size_t)i * BDIM + j;
    float t1 = 0.f, lda = 0.f, dac = 0.f;
    #pragma unroll
    for (int zz = 0; zz < 4; ++zz) {
      const size_t idx = (size_t)zz * BDIM * BDIM + o;
      t1 += t1p[idx]; lda += ldap[idx]; dac += dacp[idx];
    }
    const float bd = fmaf(0.125f, t1,
                          0.5f * (LN2 * lda - 0.5f * (l1 + ld[BDIM + j])));
    sim[o] = exp2f(bd * (-LOG2E / (float)DDIM));
    const float p = exp2f((2.0f * LOG2E) * dac);
    if (j == i) pdiag[i] = p;
    else        rmax = fmaxf(rmax, p);
  }
  __shared__ float red[4];
  const int wid = t >> 6, lane = t & 63;
  const float wm = wave_reduce_max(rmax);
  if (lane == 0) red[wid] = wm;
  __syncthreads();
  if (t == 0) pmaxf[i] = fmaxf(fmaxf(red[0], red[1]), fmaxf(red[2], red[3]));
}

// ---------------------------------------------------------------------------
// Kernel 4: per-row and per-column LSE of logits = scale*sim, plus diag.
// ---------------------------------------------------------------------------
__global__ __launch_bounds__(256) void lse_kernel(
    const float* __restrict__ sim, const float* __restrict__ lscale,
    float* __restrict__ lse_row, float* __restrict__ lse_col,
    float* __restrict__ dlog) {
  const int b = blockIdx.x;
  const int t = threadIdx.x;
  const float sc = *lscale;
  const float r0 = sc * sim[b * BDIM + t];
  const float r1 = sc * sim[b * BDIM + t + 256];
  const float c0 = sc * sim[t * BDIM + b];
  const float c1 = sc * sim[(t + 256) * BDIM + b];

  __shared__ float red[4];
  const int wid = t >> 6, lane = t & 63;

  float rm = wave_reduce_max(fmaxf(r0, r1));
  if (lane == 0) red[wid] = rm;
  __syncthreads();
  rm = fmaxf(fmaxf(red[0], red[1]), fmaxf(red[2], red[3]));
  __syncthreads();

  float cm = wave_reduce_max(fmaxf(c0, c1));
  if (lane == 0) red[wid] = cm;
  __syncthreads();
  cm = fmaxf(fmaxf(red[0], red[1]), fmaxf(red[2], red[3]));
  __syncthreads();

  float rs = wave_reduce_sum(exp2f((r0 - rm) * LOG2E) + exp2f((r1 - rm) * LOG2E));
  if (lane == 0) red[wid] = rs;
  __syncthreads();
  rs = red[0] + red[1] + red[2] + red[3];
  __syncthreads();

  float cs = wave_reduce_sum(exp2f((c0 - cm) * LOG2E) + exp2f((c1 - cm) * LOG2E));
  if (lane == 0) red[wid] = cs;
  __syncthreads();
  cs = red[0] + red[1] + red[2] + red[3];

  if (t == 0) {
    lse_row[b] = rm + LN2 * __log2f(rs);
    lse_col[b] = cm + LN2 * __log2f(cs);
    dlog[b]    = sc * sim[b * BDIM + b];
  }
}

// ---------------------------------------------------------------------------
// Kernel 5: final reductions -> 3 scalars.
// ---------------------------------------------------------------------------
__global__ __launch_bounds__(512) void final_kernel(
    const float* __restrict__ pdiag, const float* __restrict__ pmaxf,
    const float* __restrict__ mrow, const float* __restrict__ lse_row,
    const float* __restrict__ lse_col, const float* __restrict__ dlog,
    float* __restrict__ out) {
  const int t = threadIdx.x;  // 0..511
  const float pm = pmaxf[t];
  const float u  = exp2f(-(pdiag[t] / pm) * LOG2E);   // exp(-diag/negmax)
  const float as = 0.5f * (mrow[t] + mrow[BDIM + t]);

  float vals[6];
  vals[0] = u;
  vals[1] = u * u;
  vals[2] = as * as;
  vals[3] = u * as;
  vals[4] = lse_row[t] - dlog[t];
  vals[5] = lse_col[t] - dlog[t];

  __shared__ float red[6][8];
  const int wid = t >> 6, lane = t & 63;
  #pragma unroll
  for (int k = 0; k < 6; ++k) {
    const float v = wave_reduce_sum(vals[k]);
    if (lane == 0) red[k][wid] = v;
  }
  __syncthreads();
  if (t == 0) {
    float s[6];
    #pragma unroll
    for (int k = 0; k < 6; ++k) {
      float a = 0.f;
      #pragma unroll
      for (int w = 0; w < 8; ++w) a += red[k][w];
      s[k] = a;
    }
    const float mean_u = s[0] * (1.0f / BDIM);
    const float cosv = s[3] / fmaxf(sqrtf(s[1]) * sqrtf(s[2]), 1e-24f);
    out[0] = 0.5f * (s[4] + s[5]) * (1.0f / BDIM);  // loss_pro
    out[1] = 2.4f * (1.0f - cosv);                  // loss_rank * 2.4
    out[2] = 0.5f * mean_u;                         // var_loss
  }
}

extern "C" void kernel_launch(void* const* d_in, const int* in_sizes, int n_in,
                              void* d_out, int out_size, void* d_ws, size_t ws_size,
                              hipStream_t stream) {
  const float* mu1 = (const float*)d_in[0];
  const float* s1  = (const float*)d_in[1];
  const float* mu2 = (const float*)d_in[2];
  const float* s2  = (const float*)d_in[3];
  const float* lsc = (const float*)d_in[4];
  float* out = (float*)d_out;

  float* ws      = (float*)d_ws;
  float2* pA     = (float2*)ws;                       // 512*512 float2 (2MB)
  float2* pB     = pA + BDIM * DDIM;                  // 2MB
  float* sim     = (float*)(pB + BDIM * DDIM);        // 1MB
  float* t1p     = sim + BDIM * BDIM;                 // 4 * 1MB
  float* ldap    = t1p + 4 * BDIM * BDIM;             // 4 * 1MB
  float* dacp    = ldap + 4 * BDIM * BDIM;            // 4 * 1MB
  float* ld      = dacp + 4 * BDIM * BDIM;            // 2*512
  float* mrow    = ld + 2 * BDIM;                     // 2*512
  float* pmaxf   = mrow + 2 * BDIM;                   // 512
  float* pdiag   = pmaxf + BDIM;                      // 512
  float* lse_row = pdiag + BDIM;                      // 512
  float* lse_col = lse_row + BDIM;                    // 512
  float* dlog    = lse_col + BDIM;                    // 512

  prep_kernel<<<dim3(BDIM, 2), 256, 0, stream>>>(mu1, s1, mu2, s2, pA, pB,
                                                 ld, mrow);
  bd_kernel<<<dim3(16, 16, 4), 256, 0, stream>>>(pA, pB, t1p, ldap, dacp);
  combine_kernel<<<BDIM, 256, 0, stream>>>(t1p, ldap, dacp, ld, sim, pmaxf,
                                           pdiag);
  lse_kernel<<<BDIM, 256, 0, stream>>>(sim, lsc, lse_row, lse_col, dlog);
  final_kernel<<<1, 512, 0, stream>>>(pdiag, pmaxf, mrow, lse_row, lse_col,
                                      dlog, out);
}